// Round 3
// baseline (702.257 us; speedup 1.0000x reference)
//
#include <hip/hip_runtime.h>

constexpr float kEps = 1e-5f;

__device__ __forceinline__ unsigned short f2bf(float x) {
  unsigned int u = __float_as_uint(x);
  unsigned int r = (u + 0x7fffu + ((u >> 16) & 1u)) >> 16;
  return (unsigned short)r;
}
__device__ __forceinline__ float bflo(unsigned int u) { return __uint_as_float(u << 16); }
__device__ __forceinline__ float bfhi(unsigned int u) { return __uint_as_float(u & 0xffff0000u); }
__device__ __forceinline__ unsigned int packbf(float a, float b) {
  return (unsigned int)f2bf(a) | ((unsigned int)f2bf(b) << 16);
}

// ---------------- setup kernels ----------------

__global__ void zero_int2(int* __restrict__ a, int* __restrict__ b, int n) {
  int i = blockIdx.x * blockDim.x + threadIdx.x;
  if (i < n) { a[i] = 0; b[i] = 0; }
}

__global__ void hist_kernel(const int* __restrict__ dst, int* __restrict__ deg, int E) {
  int e = blockIdx.x * blockDim.x + threadIdx.x;
  if (e < E) atomicAdd(&deg[dst[e]], 1);
}

__global__ void scan1_kernel(const int* __restrict__ deg, int* __restrict__ off,
                             int* __restrict__ part, int N) {
  __shared__ int sm[1024];
  int i = blockIdx.x * 1024 + threadIdx.x;
  int v = (i < N) ? deg[i] : 0;
  sm[threadIdx.x] = v;
  __syncthreads();
  for (int o = 1; o < 1024; o <<= 1) {
    int t = (threadIdx.x >= o) ? sm[threadIdx.x - o] : 0;
    __syncthreads();
    sm[threadIdx.x] += t;
    __syncthreads();
  }
  if (i < N) off[i] = sm[threadIdx.x] - v;   // exclusive
  if (threadIdx.x == 1023) part[blockIdx.x] = sm[1023];
}

__global__ void scan2_kernel(int* __restrict__ part, int* __restrict__ off, int nb, int N) {
  if (threadIdx.x == 0) {
    int run = 0;
    for (int b = 0; b < nb; b++) { int p = part[b]; part[b] = run; run += p; }
    off[N] = run;
  }
}

__global__ void scan3_kernel(int* __restrict__ off, const int* __restrict__ part, int N) {
  int i = blockIdx.x * 1024 + threadIdx.x;
  if (i < N) off[i] += part[blockIdx.x];
}

__global__ void fill_kernel(const int* __restrict__ dst, const int* __restrict__ off,
                            int* __restrict__ cnt, int* __restrict__ edges, int E) {
  int e = blockIdx.x * blockDim.x + threadIdx.x;
  if (e < E) {
    int d = dst[e];
    int slot = off[d] + atomicAdd(&cnt[d], 1);
    edges[slot] = e;
  }
}

// deterministic edge order within each node (insertion sort; avg degree ~16)
__global__ void sort_kernel(const int* __restrict__ off, int* __restrict__ edges, int N) {
  int n = blockIdx.x * blockDim.x + threadIdx.x;
  if (n >= N) return;
  int b = off[n], e = off[n + 1];
  for (int i = b + 1; i < e; i++) {
    int key = edges[i];
    int j = i - 1;
    while (j >= b && edges[j] > key) { edges[j + 1] = edges[j]; j--; }
    edges[j + 1] = key;
  }
}

// srcs[slot] = src[edg[slot]], ews[slot] = ew[edg[slot]]  (CSR-order copies)
__global__ void gather_kernel(const int* __restrict__ edg, const int* __restrict__ src,
                              const float* __restrict__ ew, int* __restrict__ srcs,
                              float* __restrict__ ews, int E) {
  int i = blockIdx.x * blockDim.x + threadIdx.x;
  if (i < E) {
    int e = edg[i];
    srcs[i] = src[e];
    ews[i] = ew[e];
  }
}

__global__ void adl_kernel(const int* __restrict__ deg, float* __restrict__ adl, int N) {
  __shared__ float sm[1024];
  float s = 0.f;
  for (int n = threadIdx.x; n < N; n += 1024) s += logf((float)deg[n] + 1.f);
  sm[threadIdx.x] = s;
  __syncthreads();
  for (int o = 512; o > 0; o >>= 1) {
    if (threadIdx.x < o) sm[threadIdx.x] += sm[threadIdx.x + o];
    __syncthreads();
  }
  if (threadIdx.x == 0) adl[0] = sm[0];   // sum of log(deg+1); consumers divide by N
}

// h0 = x @ node_W + node_b   (x: [N,128], W: [128,32])
__global__ void node_emb_kernel(const float* __restrict__ x, const float* __restrict__ W,
                                const float* __restrict__ b, float* __restrict__ h, int N) {
  int n = blockIdx.x * 8 + (threadIdx.x >> 5);
  int j = threadIdx.x & 31;
  if (n >= N) return;
  float acc = b[j];
  const float4* x4 = (const float4*)(x + (size_t)n * 128);
#pragma unroll
  for (int q = 0; q < 32; q++) {
    float4 v = x4[q];
    acc += v.x * W[(4 * q + 0) * 32 + j];
    acc += v.y * W[(4 * q + 1) * 32 + j];
    acc += v.z * W[(4 * q + 2) * 32 + j];
    acc += v.w * W[(4 * q + 3) * 32 + j];
  }
  h[n * 32 + j] = acc;
}

// Fold edge path: Wf[l,t] = (edge_W @ enc_W[l]) @ pre_W[l,t,64:96,:]  (16x32)
//                 bf[l,t] = ((edge_b@enc_W[l]+enc_b[l]) @ pre_W[l,t,64:96,:]) + pre_b[l,t]
__global__ void fuse_kernel(const float* __restrict__ edge_W, const float* __restrict__ edge_b,
                            const float* __restrict__ enc_W, const float* __restrict__ enc_b,
                            const float* __restrict__ pre_W, const float* __restrict__ pre_b,
                            float* __restrict__ Wf, float* __restrict__ bf) {
  __shared__ float tW[2][16][32];
  __shared__ float tb[2][32];
  int tid = threadIdx.x;
  for (int i = tid; i < 1024; i += 256) {
    int l = i >> 9, r = (i >> 5) & 15, c = i & 31;
    float s = 0.f;
    for (int k = 0; k < 32; k++) s += edge_W[r * 32 + k] * enc_W[(l * 32 + k) * 32 + c];
    tW[l][r][c] = s;
  }
  for (int i = tid; i < 64; i += 256) {
    int l = i >> 5, c = i & 31;
    float s = enc_b[l * 32 + c];
    for (int k = 0; k < 32; k++) s += edge_b[k] * enc_W[(l * 32 + k) * 32 + c];
    tb[l][c] = s;
  }
  __syncthreads();
  for (int i = tid; i < 4096; i += 256) {
    int l = i >> 11, t = (i >> 9) & 3, r = (i >> 5) & 15, c = i & 31;
    float s = 0.f;
    for (int k = 0; k < 32; k++) s += tW[l][r][k] * pre_W[((l * 4 + t) * 96 + 64 + k) * 32 + c];
    Wf[i] = s;
  }
  for (int i = tid; i < 256; i += 256) {
    int l = i >> 7, t = (i >> 5) & 3, c = i & 31;
    float s = pre_b[(l * 4 + t) * 32 + c];
    for (int k = 0; k < 32; k++) s += tb[l][k] * pre_W[((l * 4 + t) * 96 + 64 + k) * 32 + c];
    bf[i] = s;
  }
}

// ---------------- per-layer: node pre-projection ----------------
__global__ __launch_bounds__(256) void prep_kernel(
    const float* __restrict__ h, const float* __restrict__ preW,
    const float* __restrict__ bfv, unsigned short* __restrict__ qB,
    unsigned short* __restrict__ AB, int N) {
  __shared__ float hs[16][32];
  int tid = threadIdx.x;
  int c = tid & 127, half = tid >> 7;
  int t = c >> 5, g = c & 31;
  float ws[32], wd[32];
  {
    const float* pS = preW + (t * 96 + 32) * 32 + g;
    const float* pD = preW + (t * 96) * 32 + g;
#pragma unroll
    for (int k = 0; k < 32; k++) { ws[k] = pS[k * 32]; wd[k] = pD[k * 32]; }
  }
  float bc = bfv[c];
  int base = blockIdx.x * 16;
  for (int i = tid; i < 512; i += 256) {
    int nn = i >> 5;
    hs[nn][i & 31] = (base + nn < N) ? h[(size_t)(base + nn) * 32 + (i & 31)] : 0.f;
  }
  __syncthreads();
#pragma unroll
  for (int nn = 0; nn < 8; ++nn) {
    int nl = half + 2 * nn;
    int n = base + nl;
    if (n >= N) continue;
    float qa = 0.f, Aa = bc;
#pragma unroll
    for (int k = 0; k < 32; k++) {
      float hk = hs[nl][k];
      qa = fmaf(hk, ws[k], qa);
      Aa = fmaf(hk, wd[k], Aa);
    }
    qB[(size_t)n * 128 + c] = f2bf(qa);
    AB[(size_t)n * 128 + c] = f2bf(Aa);
  }
}

// ---------------- per-layer: block-cooperative edge aggregation ----------------
// Block = 4 nodes. Phase 1: all 4 waves compute messages of ALL block edges in
// parallel (every 4th CSR slot) into LDS (bf16 pairs). Phase 2: wave w does the
// stats pass over its own node's slots. Chunked for LDS capacity.
#define AGG_CHUNK 96
__global__ __launch_bounds__(256) void agg2_kernel(
    const unsigned int* __restrict__ qB,   // [N][64] packed bf16 pairs
    const unsigned int* __restrict__ AB,
    const int* __restrict__ coff, const int* __restrict__ srcs,
    const float* __restrict__ ews, const int* __restrict__ edg,
    const float* __restrict__ eattr, const float* __restrict__ Wf,
    unsigned int* __restrict__ stats,      // [N][4][64] packed bf16 pairs
    int N) {
  __shared__ unsigned int vbuf[AGG_CHUNK * 64];  // 24 KB
  __shared__ unsigned int Als[4][64];            // 1 KB
  __shared__ int sb[5];
  int tid = threadIdx.x, wave = tid >> 6, lane = tid & 63;
  int nb = blockIdx.x * 4;
  if (tid < 5) sb[tid] = coff[min(nb + tid, N)];
  int n_w = nb + wave;
  if (n_w < N) Als[wave][lane] = AB[(size_t)n_w * 64 + lane];
  __syncthreads();
  int slotBeg = sb[0], c1 = sb[1], c2 = sb[2], c3 = sb[3], slotEnd = sb[4];
  int myBeg = sb[wave], myEnd = sb[min(wave + 1, 4)];

  int t = lane >> 4;            // tower of comp 2*lane
  int g0 = (2 * lane) & 31;
  float wfa[16], wfb[16];
  {
    const float* p = Wf + t * 512 + g0;
#pragma unroll
    for (int k = 0; k < 16; k++) { wfa[k] = p[k * 32]; wfb[k] = p[k * 32 + 1]; }
  }

  float s0 = 0.f, s1 = 0.f, sq0 = 0.f, sq1 = 0.f;
  float mn0 = 1e30f, mn1 = 1e30f, mx0 = -1e30f, mx1 = -1e30f;

  int total = slotEnd - slotBeg;
  int nch = (total + AGG_CHUNK - 1) / AGG_CHUNK;
  for (int ch = 0; ch < nch; ++ch) {
    int cs = slotBeg + ch * AGG_CHUNK;
    int ce = min(cs + AGG_CHUNK, slotEnd);
    // phase 1: cooperative message compute
    for (int slot = cs + wave; slot < ce; slot += 4) {
      int e = edg[slot];
      int sN = srcs[slot];
      float w = ews[slot];
      int d = (slot >= c1) + (slot >= c2) + (slot >= c3);
      unsigned int qu = qB[(size_t)sN * 64 + lane];
      unsigned int au = Als[d][lane];
      const float4* ea = (const float4*)(eattr + (size_t)e * 16);
      float4 e0 = ea[0], e1 = ea[1], e2 = ea[2], e3 = ea[3];
      float f0, f1;
      f0 = e0.x * wfa[0];  f1 = e0.x * wfb[0];
      f0 = fmaf(e0.y, wfa[1], f0);  f1 = fmaf(e0.y, wfb[1], f1);
      f0 = fmaf(e0.z, wfa[2], f0);  f1 = fmaf(e0.z, wfb[2], f1);
      f0 = fmaf(e0.w, wfa[3], f0);  f1 = fmaf(e0.w, wfb[3], f1);
      f0 = fmaf(e1.x, wfa[4], f0);  f1 = fmaf(e1.x, wfb[4], f1);
      f0 = fmaf(e1.y, wfa[5], f0);  f1 = fmaf(e1.y, wfb[5], f1);
      f0 = fmaf(e1.z, wfa[6], f0);  f1 = fmaf(e1.z, wfb[6], f1);
      f0 = fmaf(e1.w, wfa[7], f0);  f1 = fmaf(e1.w, wfb[7], f1);
      f0 = fmaf(e2.x, wfa[8], f0);  f1 = fmaf(e2.x, wfb[8], f1);
      f0 = fmaf(e2.y, wfa[9], f0);  f1 = fmaf(e2.y, wfb[9], f1);
      f0 = fmaf(e2.z, wfa[10], f0); f1 = fmaf(e2.z, wfb[10], f1);
      f0 = fmaf(e2.w, wfa[11], f0); f1 = fmaf(e2.w, wfb[11], f1);
      f0 = fmaf(e3.x, wfa[12], f0); f1 = fmaf(e3.x, wfb[12], f1);
      f0 = fmaf(e3.y, wfa[13], f0); f1 = fmaf(e3.y, wfb[13], f1);
      f0 = fmaf(e3.z, wfa[14], f0); f1 = fmaf(e3.z, wfb[14], f1);
      f0 = fmaf(e3.w, wfa[15], f0); f1 = fmaf(e3.w, wfb[15], f1);
      float v0 = (bflo(au) + bflo(qu) + f0) * w;
      float v1 = (bfhi(au) + bfhi(qu) + f1) * w;
      vbuf[(slot - cs) * 64 + lane] = packbf(v0, v1);
    }
    __syncthreads();
    // phase 2: per-node stats over my slots in this chunk
    int a = max(myBeg, cs), b = min(myEnd, ce);
    for (int slot = a; slot < b; ++slot) {
      unsigned int vu = vbuf[(slot - cs) * 64 + lane];
      float v0 = bflo(vu), v1 = bfhi(vu);
      s0 += v0; sq0 = fmaf(v0, v0, sq0); mn0 = fminf(mn0, v0); mx0 = fmaxf(mx0, v0);
      s1 += v1; sq1 = fmaf(v1, v1, sq1); mn1 = fminf(mn1, v1); mx1 = fmaxf(mx1, v1);
    }
    __syncthreads();
  }

  if (n_w >= N) return;
  int dg = myEnd - myBeg;
  if (dg == 0) { mn0 = 0.f; mx0 = 0.f; mn1 = 0.f; mx1 = 0.f; }
  float inv = 1.f / (float)(dg > 0 ? dg : 1);
  float mean0 = s0 * inv, mean1 = s1 * inv;
  float sd0 = sqrtf(fmaxf(sq0 * inv - mean0 * mean0, 0.f) + kEps);
  float sd1 = sqrtf(fmaxf(sq1 * inv - mean1 * mean1, 0.f) + kEps);
  unsigned int* sp = stats + (size_t)n_w * 256;
  sp[0 * 64 + lane] = packbf(mean0, mean1);
  sp[1 * 64 + lane] = packbf(mn0, mn1);
  sp[2 * 64 + lane] = packbf(mx0, mx1);
  sp[3 * 64 + lane] = packbf(sd0, sd1);
}

// ---------------- per-layer: post_nn + lin + BN partials ----------------
__global__ __launch_bounds__(256) void post_kernel(
    const float* __restrict__ h, const unsigned int* __restrict__ stats,
    const int* __restrict__ coff, const float* __restrict__ adl,
    const float* __restrict__ postW, const float* __restrict__ postB,
    const float* __restrict__ linW, const float* __restrict__ linB,
    float* __restrict__ pre, float* __restrict__ pb, int N) {
  __shared__ float pw[416 * 32];   // [f][t*8+q'] : 52 KB
  __shared__ float st4[4][576];    // per-wave stats; reused for BN reduce at end
  int tid = threadIdx.x;
  for (int i = tid; i < 13312; i += 256) {
    int t = i / 3328, r = i % 3328;
    int f = r >> 3, gq = r & 7;
    pw[f * 32 + t * 8 + gq] = postW[i];
  }
  __syncthreads();

  int wave = tid >> 6, lane = tid & 63;
  int c = lane & 31, hh = lane >> 5;
  int tP = c >> 3;
  float adN = adl[0];
  float* stw = st4[wave];
  float bs = 0.f, bq = 0.f;

  for (int n = blockIdx.x * 4 + wave; n < N; n += gridDim.x * 4) {
    {
      uint4 su = ((const uint4*)stats)[(size_t)n * 64 + lane];
      int b = lane >> 2;
      int gg = (lane & 3) * 8;
      float* w0 = &stw[b * 36 + gg];
      w0[0] = bflo(su.x); w0[1] = bfhi(su.x);
      w0[2] = bflo(su.y); w0[3] = bfhi(su.y);
      w0[4] = bflo(su.z); w0[5] = bfhi(su.z);
      w0[6] = bflo(su.w); w0[7] = bfhi(su.w);
    }
    int dg = coff[n + 1] - coff[n];
    float degc = (float)(dg > 0 ? dg : 1);
    float ad = adN / (float)N;
    float ld = logf(degc + 1.f);
    float amp = ld / ad, att = ad / ld;

    float acc = (hh == 0) ? postB[tP * 8 + (c & 7)] : 0.f;
    const float4* h4 = (const float4*)(h + (size_t)n * 32);
#pragma unroll
    for (int q4 = 0; q4 < 4; q4++) {
      float4 hv = h4[hh * 4 + q4];
      int k = hh * 16 + q4 * 4;
      acc = fmaf(hv.x, pw[(k + 0) * 32 + c], acc);
      acc = fmaf(hv.y, pw[(k + 1) * 32 + c], acc);
      acc = fmaf(hv.z, pw[(k + 2) * 32 + c], acc);
      acc = fmaf(hv.w, pw[(k + 3) * 32 + c], acc);
    }
#pragma unroll 4
    for (int jj = 0; jj < 64; jj++) {
      int j = hh * 64 + jj;
      float sj = stw[((j >> 5) * 4 + tP) * 36 + (j & 31)];
      float wgt = pw[(32 + j) * 32 + c];
      wgt = fmaf(amp, pw[(160 + j) * 32 + c], wgt);
      wgt = fmaf(att, pw[(288 + j) * 32 + c], wgt);
      acc = fmaf(sj, wgt, acc);
    }
    acc += __shfl_xor(acc, 32);
    float o = linB[c];
#pragma unroll
    for (int k = 0; k < 32; k++) {
      float a = __shfl(acc, k);
      o = fmaf(a, linW[k * 32 + c], o);
    }
    if (lane < 32) {
      pre[(size_t)n * 32 + c] = o;
      bs += o;
      bq = fmaf(o, o, bq);
    }
  }

  // BN partial reduce across the block's 4 waves (reuse st4 space)
  __syncthreads();
  float* red = (float*)st4;
  if (lane < 32) {
    red[(wave * 2 + 0) * 32 + c] = bs;
    red[(wave * 2 + 1) * 32 + c] = bq;
  }
  __syncthreads();
  if (tid < 64) {
    int which = tid >> 5, cc = tid & 31;
    float s = red[(0 * 2 + which) * 32 + cc] + red[(1 * 2 + which) * 32 + cc] +
              red[(2 * 2 + which) * 32 + cc] + red[(3 * 2 + which) * 32 + cc];
    pb[(size_t)blockIdx.x * 64 + which * 32 + cc] = s;
  }
}

__global__ void bn_reduce_kernel(const float* __restrict__ pb, float* __restrict__ bn, int nblk) {
  int tid = threadIdx.x;  // 256
  int col = tid & 63, grp = tid >> 6;
  float s = 0.f;
  for (int b = grp; b < nblk; b += 4) s += pb[(size_t)b * 64 + col];
  __shared__ float sm[4][64];
  sm[grp][col] = s;
  __syncthreads();
  if (tid < 64) bn[tid] = sm[0][tid] + sm[1][tid] + sm[2][tid] + sm[3][tid];
}

__global__ void bn_apply_kernel(const float* __restrict__ pre, const float* __restrict__ bn,
                                const float* __restrict__ gamma, const float* __restrict__ beta,
                                float* __restrict__ h, int N) {
  int i = blockIdx.x * 256 + threadIdx.x;
  if (i >= N * 32) return;
  int j = i & 31;
  float invN = 1.f / (float)N;
  float mu = bn[j] * invN;
  float var = bn[32 + j] * invN - mu * mu;
  float is = rsqrtf(var + kEps);
  float v = (pre[i] - mu) * is * gamma[j] + beta[j];
  h[i] = fmaxf(v, 0.f);
}

// ---------------- pooling + MLP ----------------

__device__ __forceinline__ int lower_bound_dev(const int* a, int n, int key) {
  int lo = 0, hi = n;
  while (lo < hi) {
    int m = (lo + hi) >> 1;
    if (a[m] < key) lo = m + 1; else hi = m;
  }
  return lo;
}

__global__ void pool_kernel(const float* __restrict__ h, const int* __restrict__ batch,
                            float* __restrict__ gp, int N) {
  int gi = blockIdx.x;  // 64 graphs
  int lo = lower_bound_dev(batch, N, gi);
  int hi = lower_bound_dev(batch, N, gi + 1);
  __shared__ float part[8][32];
  int j = threadIdx.x & 31, ch = threadIdx.x >> 5;
  float s = 0.f;
  for (int n = lo + ch; n < hi; n += 8) s += h[(size_t)n * 32 + j];
  part[ch][j] = s;
  __syncthreads();
  if (threadIdx.x < 32) {
    float t = 0.f;
    for (int c2 = 0; c2 < 8; c2++) t += part[c2][j];
    gp[gi * 32 + j] = t;
  }
}

__global__ void mlp_kernel(const float* __restrict__ gp,
                           const float* __restrict__ W1, const float* __restrict__ b1,
                           const float* __restrict__ W2, const float* __restrict__ b2,
                           const float* __restrict__ W3, const float* __restrict__ b3,
                           float* __restrict__ out) {
  __shared__ float g1[64 * 32];
  __shared__ float g2[64 * 16];
  int tid = threadIdx.x;  // 256
  for (int i = tid; i < 2048; i += 256) {
    int r = i >> 5, c = i & 31;
    float s = b1[c];
    for (int k = 0; k < 32; k++) s += gp[r * 32 + k] * W1[k * 32 + c];
    g1[i] = fmaxf(s, 0.f);
  }
  __syncthreads();
  for (int i = tid; i < 1024; i += 256) {
    int r = i >> 4, c = i & 15;
    float s = b2[c];
    for (int k = 0; k < 32; k++) s += g1[r * 32 + k] * W2[k * 16 + c];
    g2[i] = fmaxf(s, 0.f);
  }
  __syncthreads();
  if (tid < 64) {
    float s = b3[0];
    for (int k = 0; k < 16; k++) s += g2[tid * 16 + k] * W3[k];
    out[tid] = s;
  }
}

// ---------------- launch ----------------

extern "C" void kernel_launch(void* const* d_in, const int* in_sizes, int n_in,
                              void* d_out, int out_size, void* d_ws, size_t ws_size,
                              hipStream_t stream) {
  (void)n_in; (void)out_size; (void)ws_size;
  const float* x     = (const float*)d_in[0];
  const float* eattr = (const float*)d_in[1];
  const float* ew    = (const float*)d_in[2];
  const int*   eidx  = (const int*)d_in[3];
  const int*   batch = (const int*)d_in[4];
  const float* nodeW = (const float*)d_in[5];
  const float* nodeB = (const float*)d_in[6];
  const float* edgeW = (const float*)d_in[7];
  const float* edgeB = (const float*)d_in[8];
  const float* encW  = (const float*)d_in[9];
  const float* encB  = (const float*)d_in[10];
  const float* preW  = (const float*)d_in[11];
  const float* preB  = (const float*)d_in[12];
  const float* postW = (const float*)d_in[13];
  const float* postB = (const float*)d_in[14];
  const float* linW  = (const float*)d_in[15];
  const float* linB  = (const float*)d_in[16];
  const float* bnG   = (const float*)d_in[17];
  const float* bnB   = (const float*)d_in[18];
  const float* W1    = (const float*)d_in[19];
  const float* b1    = (const float*)d_in[20];
  const float* W2    = (const float*)d_in[21];
  const float* b2    = (const float*)d_in[22];
  const float* W3    = (const float*)d_in[23];
  const float* b3    = (const float*)d_in[24];
  float* out = (float*)d_out;

  int N = in_sizes[0] / 128;
  int E = in_sizes[2];
  const int* srcp = eidx;
  const int* dstp = eidx + E;

  char* wsb = (char*)d_ws;
  size_t woff = 0;
  auto alloc = [&](size_t bytes) -> void* {
    void* p = (void*)(wsb + woff);
    woff += (bytes + 255) & ~(size_t)255;
    return p;
  };
  int* deg   = (int*)alloc((size_t)N * 4);
  int* cnt   = (int*)alloc((size_t)N * 4);
  int* coff  = (int*)alloc((size_t)(N + 1) * 4);
  int* part  = (int*)alloc(64 * 4);
  int* edg   = (int*)alloc((size_t)E * 4);
  int* srcs  = (int*)alloc((size_t)E * 4);
  float* ews = (float*)alloc((size_t)E * 4);
  float* h    = (float*)alloc((size_t)N * 32 * 4);
  float* pre  = (float*)alloc((size_t)N * 32 * 4);
  float* adl  = (float*)alloc(256);
  float* bn   = (float*)alloc(64 * 4);
  float* gp   = (float*)alloc(64 * 32 * 4);
  float* WfB  = (float*)alloc(2 * 4 * 16 * 32 * 4);
  float* bfB  = (float*)alloc(2 * 4 * 32 * 4);
  unsigned short* qB  = (unsigned short*)alloc((size_t)N * 128 * 2);
  unsigned short* AB  = (unsigned short*)alloc((size_t)N * 128 * 2);
  unsigned int* stats = (unsigned int*)alloc((size_t)N * 256 * 4);  // [N][4][64] uints
  float* pbuf = (float*)alloc(512 * 64 * 4);

  int nb = (N + 1023) / 1024;
  zero_int2<<<(N + 255) / 256, 256, 0, stream>>>(deg, cnt, N);
  hist_kernel<<<(E + 255) / 256, 256, 0, stream>>>(dstp, deg, E);
  scan1_kernel<<<nb, 1024, 0, stream>>>(deg, coff, part, N);
  scan2_kernel<<<1, 64, 0, stream>>>(part, coff, nb, N);
  scan3_kernel<<<nb, 1024, 0, stream>>>(coff, part, N);
  fill_kernel<<<(E + 255) / 256, 256, 0, stream>>>(dstp, coff, cnt, edg, E);
  sort_kernel<<<(N + 255) / 256, 256, 0, stream>>>(coff, edg, N);
  gather_kernel<<<(E + 255) / 256, 256, 0, stream>>>(edg, srcp, ew, srcs, ews, E);
  adl_kernel<<<1, 1024, 0, stream>>>(deg, adl, N);
  node_emb_kernel<<<(N + 7) / 8, 256, 0, stream>>>(x, nodeW, nodeB, h, N);
  fuse_kernel<<<1, 256, 0, stream>>>(edgeW, edgeB, encW, encB, preW, preB, WfB, bfB);

  for (int l = 0; l < 2; l++) {
    prep_kernel<<<(N + 15) / 16, 256, 0, stream>>>(
        h, preW + (size_t)l * 12288, bfB + (size_t)l * 128, qB, AB, N);
    agg2_kernel<<<(N + 3) / 4, 256, 0, stream>>>(
        (const unsigned int*)qB, (const unsigned int*)AB, coff, srcs, ews, edg,
        eattr, WfB + (size_t)l * 2048, stats, N);
    post_kernel<<<512, 256, 0, stream>>>(
        h, stats, coff, adl,
        postW + (size_t)l * 13312, postB + (size_t)l * 32,
        linW + (size_t)l * 1024, linB + (size_t)l * 32, pre, pbuf, N);
    bn_reduce_kernel<<<1, 256, 0, stream>>>(pbuf, bn, 512);
    bn_apply_kernel<<<(N * 32 + 255) / 256, 256, 0, stream>>>(pre, bn, bnG + (size_t)l * 32,
                                                              bnB + (size_t)l * 32, h, N);
  }
  pool_kernel<<<64, 256, 0, stream>>>(h, batch, gp, N);
  mlp_kernel<<<1, 256, 0, stream>>>(gp, W1, b1, W2, b2, W3, b3, out);
}

// Round 4
// 670.065 us; speedup vs baseline: 1.0480x; 1.0480x over previous
//
#include <hip/hip_runtime.h>

constexpr float kEps = 1e-5f;

__device__ __forceinline__ unsigned short f2bf(float x) {
  unsigned int u = __float_as_uint(x);
  unsigned int r = (u + 0x7fffu + ((u >> 16) & 1u)) >> 16;
  return (unsigned short)r;
}
__device__ __forceinline__ float bflo(unsigned int u) { return __uint_as_float(u << 16); }
__device__ __forceinline__ float bfhi(unsigned int u) { return __uint_as_float(u & 0xffff0000u); }
__device__ __forceinline__ unsigned int packbf(float a, float b) {
  return (unsigned int)f2bf(a) | ((unsigned int)f2bf(b) << 16);
}

// ---------------- setup kernels ----------------

__global__ void zero_int2(int* __restrict__ a, int* __restrict__ b, int n) {
  int i = blockIdx.x * blockDim.x + threadIdx.x;
  if (i < n) { a[i] = 0; b[i] = 0; }
}

__global__ void hist_kernel(const int* __restrict__ dst, int* __restrict__ deg, int E) {
  int e = blockIdx.x * blockDim.x + threadIdx.x;
  if (e < E) atomicAdd(&deg[dst[e]], 1);
}

__global__ void scan1_kernel(const int* __restrict__ deg, int* __restrict__ off,
                             int* __restrict__ part, int N) {
  __shared__ int sm[1024];
  int i = blockIdx.x * 1024 + threadIdx.x;
  int v = (i < N) ? deg[i] : 0;
  sm[threadIdx.x] = v;
  __syncthreads();
  for (int o = 1; o < 1024; o <<= 1) {
    int t = (threadIdx.x >= o) ? sm[threadIdx.x - o] : 0;
    __syncthreads();
    sm[threadIdx.x] += t;
    __syncthreads();
  }
  if (i < N) off[i] = sm[threadIdx.x] - v;   // exclusive
  if (threadIdx.x == 1023) part[blockIdx.x] = sm[1023];
}

__global__ void scan2_kernel(int* __restrict__ part, int* __restrict__ off, int nb, int N) {
  if (threadIdx.x == 0) {
    int run = 0;
    for (int b = 0; b < nb; b++) { int p = part[b]; part[b] = run; run += p; }
    off[N] = run;
  }
}

__global__ void scan3_kernel(int* __restrict__ off, const int* __restrict__ part, int N) {
  int i = blockIdx.x * 1024 + threadIdx.x;
  if (i < N) off[i] += part[blockIdx.x];
}

// CSR fill with direct scatter of src/dst/ew (edge order within node = atomic
// arrival order; only perturbs fp reduction order at ulp level)
__global__ void fill_kernel(const int* __restrict__ src, const int* __restrict__ dst,
                            const float* __restrict__ ew, const int* __restrict__ off,
                            int* __restrict__ cnt, int* __restrict__ edg,
                            int* __restrict__ srcs, int* __restrict__ dsts,
                            float* __restrict__ ews, int E) {
  int e = blockIdx.x * blockDim.x + threadIdx.x;
  if (e < E) {
    int d = dst[e];
    int slot = off[d] + atomicAdd(&cnt[d], 1);
    edg[slot] = e;
    srcs[slot] = src[e];
    dsts[slot] = d;
    ews[slot] = ew[e];
  }
}

__global__ void adl_kernel(const int* __restrict__ deg, float* __restrict__ adl, int N) {
  __shared__ float sm[1024];
  float s = 0.f;
  for (int n = threadIdx.x; n < N; n += 1024) s += logf((float)deg[n] + 1.f);
  sm[threadIdx.x] = s;
  __syncthreads();
  for (int o = 512; o > 0; o >>= 1) {
    if (threadIdx.x < o) sm[threadIdx.x] += sm[threadIdx.x + o];
    __syncthreads();
  }
  if (threadIdx.x == 0) adl[0] = sm[0];   // sum of log(deg+1); consumers divide by N
}

// h0 = x @ node_W + node_b   (x: [N,128], W: [128,32])
__global__ void node_emb_kernel(const float* __restrict__ x, const float* __restrict__ W,
                                const float* __restrict__ b, float* __restrict__ h, int N) {
  int n = blockIdx.x * 8 + (threadIdx.x >> 5);
  int j = threadIdx.x & 31;
  if (n >= N) return;
  float acc = b[j];
  const float4* x4 = (const float4*)(x + (size_t)n * 128);
#pragma unroll
  for (int q = 0; q < 32; q++) {
    float4 v = x4[q];
    acc += v.x * W[(4 * q + 0) * 32 + j];
    acc += v.y * W[(4 * q + 1) * 32 + j];
    acc += v.z * W[(4 * q + 2) * 32 + j];
    acc += v.w * W[(4 * q + 3) * 32 + j];
  }
  h[n * 32 + j] = acc;
}

// Fold edge path: Wf[l,t] = (edge_W @ enc_W[l]) @ pre_W[l,t,64:96,:]  (16x32)
__global__ void fuse_kernel(const float* __restrict__ edge_W, const float* __restrict__ edge_b,
                            const float* __restrict__ enc_W, const float* __restrict__ enc_b,
                            const float* __restrict__ pre_W, const float* __restrict__ pre_b,
                            float* __restrict__ Wf, float* __restrict__ bf) {
  __shared__ float tW[2][16][32];
  __shared__ float tb[2][32];
  int tid = threadIdx.x;
  for (int i = tid; i < 1024; i += 256) {
    int l = i >> 9, r = (i >> 5) & 15, c = i & 31;
    float s = 0.f;
    for (int k = 0; k < 32; k++) s += edge_W[r * 32 + k] * enc_W[(l * 32 + k) * 32 + c];
    tW[l][r][c] = s;
  }
  for (int i = tid; i < 64; i += 256) {
    int l = i >> 5, c = i & 31;
    float s = enc_b[l * 32 + c];
    for (int k = 0; k < 32; k++) s += edge_b[k] * enc_W[(l * 32 + k) * 32 + c];
    tb[l][c] = s;
  }
  __syncthreads();
  for (int i = tid; i < 4096; i += 256) {
    int l = i >> 11, t = (i >> 9) & 3, r = (i >> 5) & 15, c = i & 31;
    float s = 0.f;
    for (int k = 0; k < 32; k++) s += tW[l][r][k] * pre_W[((l * 4 + t) * 96 + 64 + k) * 32 + c];
    Wf[i] = s;
  }
  for (int i = tid; i < 256; i += 256) {
    int l = i >> 7, t = (i >> 5) & 3, c = i & 31;
    float s = pre_b[(l * 4 + t) * 32 + c];
    for (int k = 0; k < 32; k++) s += tb[l][k] * pre_W[((l * 4 + t) * 96 + 64 + k) * 32 + c];
    bf[i] = s;
  }
}

// ---------------- per-layer: node pre-projection ----------------
__global__ __launch_bounds__(256) void prep_kernel(
    const float* __restrict__ h, const float* __restrict__ preW,
    const float* __restrict__ bfv, unsigned short* __restrict__ qB,
    unsigned short* __restrict__ AB, int N) {
  __shared__ float hs[16][32];
  int tid = threadIdx.x;
  int c = tid & 127, half = tid >> 7;
  int t = c >> 5, g = c & 31;
  float ws[32], wd[32];
  {
    const float* pS = preW + (t * 96 + 32) * 32 + g;
    const float* pD = preW + (t * 96) * 32 + g;
#pragma unroll
    for (int k = 0; k < 32; k++) { ws[k] = pS[k * 32]; wd[k] = pD[k * 32]; }
  }
  float bc = bfv[c];
  int base = blockIdx.x * 16;
  for (int i = tid; i < 512; i += 256) {
    int nn = i >> 5;
    hs[nn][i & 31] = (base + nn < N) ? h[(size_t)(base + nn) * 32 + (i & 31)] : 0.f;
  }
  __syncthreads();
#pragma unroll
  for (int nn = 0; nn < 8; ++nn) {
    int nl = half + 2 * nn;
    int n = base + nl;
    if (n >= N) continue;
    float qa = 0.f, Aa = bc;
#pragma unroll
    for (int k = 0; k < 32; k++) {
      float hk = hs[nl][k];
      qa = fmaf(hk, ws[k], qa);
      Aa = fmaf(hk, wd[k], Aa);
    }
    qB[(size_t)n * 128 + c] = f2bf(qa);
    AB[(size_t)n * 128 + c] = f2bf(Aa);
  }
}

// ---------------- per-layer: edge-parallel message kernel ----------------
// wave w handles 16 contiguous CSR slots of chunk [n0,n1); fully independent
// wave-tasks, no LDS, no serial per-node chain -> TLP hides all gather latency.
__global__ __launch_bounds__(256) void msg_kernel(
    const unsigned int* __restrict__ qB, const unsigned int* __restrict__ AB,
    const int* __restrict__ edg, const int* __restrict__ srcs,
    const int* __restrict__ dsts, const float* __restrict__ ews,
    const float* __restrict__ eattr, const float* __restrict__ Wf,
    const int* __restrict__ coff, unsigned int* __restrict__ msg,
    int n0, int n1, int bound) {
  int lane = threadIdx.x & 63;
  int wv = (blockIdx.x * blockDim.x + threadIdx.x) >> 6;
  int s0 = coff[n0], s1 = coff[n1];
  int base = s0 + wv * 16;
  if (base >= s1) return;
  int end = min(base + 16, s1);

  int t = lane >> 4;            // tower of comp 2*lane
  int g0 = (2 * lane) & 31;
  float wfa[16], wfb[16];
  {
    const float* p = Wf + t * 512 + g0;
#pragma unroll
    for (int k = 0; k < 16; k++) { wfa[k] = p[k * 32]; wfb[k] = p[k * 32 + 1]; }
  }
  for (int s = base; s < end; ++s) {
    int e = edg[s], sN = srcs[s], d = dsts[s];
    float w = ews[s];
    unsigned int qu = qB[(size_t)sN * 64 + lane];
    unsigned int au = AB[(size_t)d * 64 + lane];
    const float4* ea = (const float4*)(eattr + (size_t)e * 16);
    float4 e0 = ea[0], e1 = ea[1], e2 = ea[2], e3 = ea[3];
    float f0, f1;
    f0 = e0.x * wfa[0];  f1 = e0.x * wfb[0];
    f0 = fmaf(e0.y, wfa[1], f0);  f1 = fmaf(e0.y, wfb[1], f1);
    f0 = fmaf(e0.z, wfa[2], f0);  f1 = fmaf(e0.z, wfb[2], f1);
    f0 = fmaf(e0.w, wfa[3], f0);  f1 = fmaf(e0.w, wfb[3], f1);
    f0 = fmaf(e1.x, wfa[4], f0);  f1 = fmaf(e1.x, wfb[4], f1);
    f0 = fmaf(e1.y, wfa[5], f0);  f1 = fmaf(e1.y, wfb[5], f1);
    f0 = fmaf(e1.z, wfa[6], f0);  f1 = fmaf(e1.z, wfb[6], f1);
    f0 = fmaf(e1.w, wfa[7], f0);  f1 = fmaf(e1.w, wfb[7], f1);
    f0 = fmaf(e2.x, wfa[8], f0);  f1 = fmaf(e2.x, wfb[8], f1);
    f0 = fmaf(e2.y, wfa[9], f0);  f1 = fmaf(e2.y, wfb[9], f1);
    f0 = fmaf(e2.z, wfa[10], f0); f1 = fmaf(e2.z, wfb[10], f1);
    f0 = fmaf(e2.w, wfa[11], f0); f1 = fmaf(e2.w, wfb[11], f1);
    f0 = fmaf(e3.x, wfa[12], f0); f1 = fmaf(e3.x, wfb[12], f1);
    f0 = fmaf(e3.y, wfa[13], f0); f1 = fmaf(e3.y, wfb[13], f1);
    f0 = fmaf(e3.z, wfa[14], f0); f1 = fmaf(e3.z, wfb[14], f1);
    f0 = fmaf(e3.w, wfa[15], f0); f1 = fmaf(e3.w, wfb[15], f1);
    float v0 = (bflo(au) + bflo(qu) + f0) * w;
    float v1 = (bfhi(au) + bfhi(qu) + f1) * w;
    int idx = s - s0;
    if (idx < bound) msg[(size_t)idx * 64 + lane] = packbf(v0, v1);
  }
}

// ---------------- per-layer: per-node streaming stats ----------------
__global__ __launch_bounds__(256) void stats_kernel(
    const unsigned int* __restrict__ msg, const int* __restrict__ coff,
    unsigned int* __restrict__ stats, int n0, int n1, int bound) {
  int lane = threadIdx.x & 63;
  int wv = (blockIdx.x * blockDim.x + threadIdx.x) >> 6;
  int n = n0 + wv;
  if (n >= n1) return;
  int s0 = coff[n0];
  int beg = coff[n], end = coff[n + 1];
  int dg = end - beg;
  int bm = bound - 1;

  float s0a = 0.f, s1a = 0.f, sq0 = 0.f, sq1 = 0.f;
  float mn0 = 1e30f, mn1 = 1e30f, mx0 = -1e30f, mx1 = -1e30f;
  int i = beg;
  for (; i + 4 <= end; i += 4) {
    unsigned int u0 = msg[(size_t)min(i + 0 - s0, bm) * 64 + lane];
    unsigned int u1 = msg[(size_t)min(i + 1 - s0, bm) * 64 + lane];
    unsigned int u2 = msg[(size_t)min(i + 2 - s0, bm) * 64 + lane];
    unsigned int u3 = msg[(size_t)min(i + 3 - s0, bm) * 64 + lane];
#pragma unroll
    for (int q = 0; q < 4; q++) {
      unsigned int u = (q == 0) ? u0 : (q == 1) ? u1 : (q == 2) ? u2 : u3;
      float v0 = bflo(u), v1 = bfhi(u);
      s0a += v0; sq0 = fmaf(v0, v0, sq0); mn0 = fminf(mn0, v0); mx0 = fmaxf(mx0, v0);
      s1a += v1; sq1 = fmaf(v1, v1, sq1); mn1 = fminf(mn1, v1); mx1 = fmaxf(mx1, v1);
    }
  }
  for (; i < end; ++i) {
    unsigned int u = msg[(size_t)min(i - s0, bm) * 64 + lane];
    float v0 = bflo(u), v1 = bfhi(u);
    s0a += v0; sq0 = fmaf(v0, v0, sq0); mn0 = fminf(mn0, v0); mx0 = fmaxf(mx0, v0);
    s1a += v1; sq1 = fmaf(v1, v1, sq1); mn1 = fminf(mn1, v1); mx1 = fmaxf(mx1, v1);
  }
  if (dg == 0) { mn0 = 0.f; mx0 = 0.f; mn1 = 0.f; mx1 = 0.f; }
  float inv = 1.f / (float)(dg > 0 ? dg : 1);
  float mean0 = s0a * inv, mean1 = s1a * inv;
  float sd0 = sqrtf(fmaxf(sq0 * inv - mean0 * mean0, 0.f) + kEps);
  float sd1 = sqrtf(fmaxf(sq1 * inv - mean1 * mean1, 0.f) + kEps);
  unsigned int* sp = stats + (size_t)n * 256;
  sp[0 * 64 + lane] = packbf(mean0, mean1);
  sp[1 * 64 + lane] = packbf(mn0, mn1);
  sp[2 * 64 + lane] = packbf(mx0, mx1);
  sp[3 * 64 + lane] = packbf(sd0, sd1);
}

// ---------------- per-layer: post_nn + lin + BN partials ----------------
// post_W staged packed-bf16 (26 KB LDS), stats kept as packed uints (4 KB).
__global__ __launch_bounds__(256) void post_kernel(
    const float* __restrict__ h, const unsigned int* __restrict__ stats,
    const int* __restrict__ coff, const float* __restrict__ adl,
    const float* __restrict__ postW, const float* __restrict__ postB,
    const float* __restrict__ linW, const float* __restrict__ linB,
    float* __restrict__ pre, float* __restrict__ pb, int N) {
  __shared__ unsigned int pwp[208 * 32];   // rows paired (2r,2r+1): 26 KB
  __shared__ unsigned int stu[4][256];     // per-wave raw stats rows: 4 KB
  __shared__ float red[8][32];             // BN partial reduce: 1 KB
  int tid = threadIdx.x;
  for (int i = tid; i < 6656; i += 256) {
    int r = i >> 5, cc = i & 31, tP = cc >> 3, gq = cc & 7;
    float lo = postW[tP * 3328 + (2 * r) * 8 + gq];
    float hi = postW[tP * 3328 + (2 * r + 1) * 8 + gq];
    pwp[i] = packbf(lo, hi);
  }
  __syncthreads();

  int wave = tid >> 6, lane = tid & 63;
  int c = lane & 31, hh = lane >> 5;
  int tP = c >> 3;
  float adN = adl[0];
  float bs = 0.f, bq = 0.f;

  for (int n = blockIdx.x * 4 + wave; n < N; n += gridDim.x * 4) {
    {
      uint4 su = ((const uint4*)stats)[(size_t)n * 64 + lane];
      ((uint4*)stu[wave])[lane] = su;   // per-wave region: no block barrier needed
    }
    int dg = coff[n + 1] - coff[n];
    float degc = (float)(dg > 0 ? dg : 1);
    float ad = adN / (float)N;
    float ld = logf(degc + 1.f);
    float amp = ld / ad, att = ad / ld;

    float acc = (hh == 0) ? postB[tP * 8 + (c & 7)] : 0.f;
    const float4* h4 = (const float4*)(h + (size_t)n * 32);
#pragma unroll
    for (int q4 = 0; q4 < 4; q4++) {
      float4 hv = h4[hh * 4 + q4];
      int r0 = hh * 8 + q4 * 2;
      unsigned int u0 = pwp[r0 * 32 + c], u1 = pwp[(r0 + 1) * 32 + c];
      acc = fmaf(hv.x, bflo(u0), acc);
      acc = fmaf(hv.y, bfhi(u0), acc);
      acc = fmaf(hv.z, bflo(u1), acc);
      acc = fmaf(hv.w, bfhi(u1), acc);
    }
#pragma unroll 8
    for (int jj = 0; jj < 32; jj++) {
      int sIdx = hh * 2 + (jj >> 4);
      unsigned int sv = stu[wave][sIdx * 64 + tP * 16 + (jj & 15)];
      float v0 = bflo(sv), v1 = bfhi(sv);
      int rm = 16 + hh * 32 + jj, ra = 80 + hh * 32 + jj, rt = 144 + hh * 32 + jj;
      unsigned int um = pwp[rm * 32 + c];
      unsigned int ua = pwp[ra * 32 + c];
      unsigned int ut = pwp[rt * 32 + c];
      float w0 = bflo(um); w0 = fmaf(amp, bflo(ua), w0); w0 = fmaf(att, bflo(ut), w0);
      float w1 = bfhi(um); w1 = fmaf(amp, bfhi(ua), w1); w1 = fmaf(att, bfhi(ut), w1);
      acc = fmaf(v0, w0, acc);
      acc = fmaf(v1, w1, acc);
    }
    acc += __shfl_xor(acc, 32);
    float o = linB[c];
#pragma unroll
    for (int k = 0; k < 32; k++) {
      float a = __shfl(acc, k);
      o = fmaf(a, linW[k * 32 + c], o);
    }
    if (lane < 32) {
      pre[(size_t)n * 32 + c] = o;
      bs += o;
      bq = fmaf(o, o, bq);
    }
  }

  __syncthreads();
  if (lane < 32) {
    red[wave * 2 + 0][c] = bs;
    red[wave * 2 + 1][c] = bq;
  }
  __syncthreads();
  if (tid < 64) {
    int which = tid >> 5, cc = tid & 31;
    float s = red[0 * 2 + which][cc] + red[1 * 2 + which][cc] +
              red[2 * 2 + which][cc] + red[3 * 2 + which][cc];
    pb[(size_t)blockIdx.x * 64 + which * 32 + cc] = s;
  }
}

__global__ void bn_reduce_kernel(const float* __restrict__ pb, float* __restrict__ bn, int nblk) {
  int tid = threadIdx.x;  // 256
  int col = tid & 63, grp = tid >> 6;
  float s = 0.f;
  for (int b = grp; b < nblk; b += 4) s += pb[(size_t)b * 64 + col];
  __shared__ float sm[4][64];
  sm[grp][col] = s;
  __syncthreads();
  if (tid < 64) bn[tid] = sm[0][tid] + sm[1][tid] + sm[2][tid] + sm[3][tid];
}

__global__ void bn_apply_kernel(const float* __restrict__ pre, const float* __restrict__ bn,
                                const float* __restrict__ gamma, const float* __restrict__ beta,
                                float* __restrict__ h, int N) {
  int i = blockIdx.x * 256 + threadIdx.x;
  if (i >= N * 32) return;
  int j = i & 31;
  float invN = 1.f / (float)N;
  float mu = bn[j] * invN;
  float var = bn[32 + j] * invN - mu * mu;
  float is = rsqrtf(var + kEps);
  float v = (pre[i] - mu) * is * gamma[j] + beta[j];
  h[i] = fmaxf(v, 0.f);
}

// ---------------- pooling + MLP ----------------

__device__ __forceinline__ int lower_bound_dev(const int* a, int n, int key) {
  int lo = 0, hi = n;
  while (lo < hi) {
    int m = (lo + hi) >> 1;
    if (a[m] < key) lo = m + 1; else hi = m;
  }
  return lo;
}

__global__ void pool_kernel(const float* __restrict__ h, const int* __restrict__ batch,
                            float* __restrict__ gp, int N) {
  int gi = blockIdx.x;  // 64 graphs
  int lo = lower_bound_dev(batch, N, gi);
  int hi = lower_bound_dev(batch, N, gi + 1);
  __shared__ float part[8][32];
  int j = threadIdx.x & 31, ch = threadIdx.x >> 5;
  float s = 0.f;
  for (int n = lo + ch; n < hi; n += 8) s += h[(size_t)n * 32 + j];
  part[ch][j] = s;
  __syncthreads();
  if (threadIdx.x < 32) {
    float t = 0.f;
    for (int c2 = 0; c2 < 8; c2++) t += part[c2][j];
    gp[gi * 32 + j] = t;
  }
}

__global__ void mlp_kernel(const float* __restrict__ gp,
                           const float* __restrict__ W1, const float* __restrict__ b1,
                           const float* __restrict__ W2, const float* __restrict__ b2,
                           const float* __restrict__ W3, const float* __restrict__ b3,
                           float* __restrict__ out) {
  __shared__ float g1[64 * 32];
  __shared__ float g2[64 * 16];
  int tid = threadIdx.x;  // 256
  for (int i = tid; i < 2048; i += 256) {
    int r = i >> 5, c = i & 31;
    float s = b1[c];
    for (int k = 0; k < 32; k++) s += gp[r * 32 + k] * W1[k * 32 + c];
    g1[i] = fmaxf(s, 0.f);
  }
  __syncthreads();
  for (int i = tid; i < 1024; i += 256) {
    int r = i >> 4, c = i & 15;
    float s = b2[c];
    for (int k = 0; k < 32; k++) s += g1[r * 32 + k] * W2[k * 16 + c];
    g2[i] = fmaxf(s, 0.f);
  }
  __syncthreads();
  if (tid < 64) {
    float s = b3[0];
    for (int k = 0; k < 16; k++) s += g2[tid * 16 + k] * W3[k];
    out[tid] = s;
  }
}

// ---------------- launch ----------------

extern "C" void kernel_launch(void* const* d_in, const int* in_sizes, int n_in,
                              void* d_out, int out_size, void* d_ws, size_t ws_size,
                              hipStream_t stream) {
  (void)n_in; (void)out_size;
  const float* x     = (const float*)d_in[0];
  const float* eattr = (const float*)d_in[1];
  const float* ew    = (const float*)d_in[2];
  const int*   eidx  = (const int*)d_in[3];
  const int*   batch = (const int*)d_in[4];
  const float* nodeW = (const float*)d_in[5];
  const float* nodeB = (const float*)d_in[6];
  const float* edgeW = (const float*)d_in[7];
  const float* edgeB = (const float*)d_in[8];
  const float* encW  = (const float*)d_in[9];
  const float* encB  = (const float*)d_in[10];
  const float* preW  = (const float*)d_in[11];
  const float* preB  = (const float*)d_in[12];
  const float* postW = (const float*)d_in[13];
  const float* postB = (const float*)d_in[14];
  const float* linW  = (const float*)d_in[15];
  const float* linB  = (const float*)d_in[16];
  const float* bnG   = (const float*)d_in[17];
  const float* bnB   = (const float*)d_in[18];
  const float* W1    = (const float*)d_in[19];
  const float* b1    = (const float*)d_in[20];
  const float* W2    = (const float*)d_in[21];
  const float* b2    = (const float*)d_in[22];
  const float* W3    = (const float*)d_in[23];
  const float* b3    = (const float*)d_in[24];
  float* out = (float*)d_out;

  int N = in_sizes[0] / 128;
  int E = in_sizes[2];
  const int* srcp = eidx;
  const int* dstp = eidx + E;

  char* wsb = (char*)d_ws;
  size_t woff = 0;
  auto alloc = [&](size_t bytes) -> void* {
    void* p = (void*)(wsb + woff);
    woff += (bytes + 255) & ~(size_t)255;
    return p;
  };
  int* deg   = (int*)alloc((size_t)N * 4);
  int* cnt   = (int*)alloc((size_t)N * 4);
  int* coff  = (int*)alloc((size_t)(N + 1) * 4);
  int* part  = (int*)alloc(64 * 4);
  int* edg   = (int*)alloc((size_t)E * 4);
  int* srcs  = (int*)alloc((size_t)E * 4);
  int* dsts  = (int*)alloc((size_t)E * 4);
  float* ews = (float*)alloc((size_t)E * 4);
  float* h    = (float*)alloc((size_t)N * 32 * 4);
  float* pre  = (float*)alloc((size_t)N * 32 * 4);
  float* adl  = (float*)alloc(256);
  float* bn   = (float*)alloc(64 * 4);
  float* gp   = (float*)alloc(64 * 32 * 4);
  float* WfB  = (float*)alloc(2 * 4 * 16 * 32 * 4);
  float* bfB  = (float*)alloc(2 * 4 * 32 * 4);
  unsigned short* qB  = (unsigned short*)alloc((size_t)N * 128 * 2);
  unsigned short* AB  = (unsigned short*)alloc((size_t)N * 128 * 2);
  unsigned int* stats = (unsigned int*)alloc((size_t)N * 256 * 4);
  float* pbuf = (float*)alloc(1280 * 64 * 4);

  // adaptive msg chunking based on remaining workspace
  size_t fixed = woff;
  size_t avail = (ws_size > fixed + (1u << 20)) ? (ws_size - fixed - (1u << 20)) : 0;
  size_t cap_slots = avail / 256;
  int k = 1;
  if (cap_slots < (size_t)E) {
    for (k = 2; k <= 64; ++k) {
      size_t b = (size_t)E / k + (size_t)E / (k * 16) + 4096;
      if (b <= cap_slots) break;
    }
  }
  int bound = (k == 1) ? E : (int)((size_t)E / k + (size_t)E / (k * 16) + 4096);
  unsigned int* msg = (unsigned int*)alloc((size_t)bound * 256);
  int ncn = (N + k - 1) / k;            // nodes per chunk
  int grid_m = (bound + 63) / 64;       // 4 waves x 16 slots per block
  int grid_s = (ncn + 3) / 4;

  int nb = (N + 1023) / 1024;
  zero_int2<<<(N + 255) / 256, 256, 0, stream>>>(deg, cnt, N);
  hist_kernel<<<(E + 255) / 256, 256, 0, stream>>>(dstp, deg, E);
  scan1_kernel<<<nb, 1024, 0, stream>>>(deg, coff, part, N);
  scan2_kernel<<<1, 64, 0, stream>>>(part, coff, nb, N);
  scan3_kernel<<<nb, 1024, 0, stream>>>(coff, part, N);
  fill_kernel<<<(E + 255) / 256, 256, 0, stream>>>(srcp, dstp, ew, coff, cnt, edg, srcs, dsts, ews, E);
  adl_kernel<<<1, 1024, 0, stream>>>(deg, adl, N);
  node_emb_kernel<<<(N + 7) / 8, 256, 0, stream>>>(x, nodeW, nodeB, h, N);
  fuse_kernel<<<1, 256, 0, stream>>>(edgeW, edgeB, encW, encB, preW, preB, WfB, bfB);

  for (int l = 0; l < 2; l++) {
    prep_kernel<<<(N + 15) / 16, 256, 0, stream>>>(
        h, preW + (size_t)l * 12288, bfB + (size_t)l * 128, qB, AB, N);
    for (int c = 0; c < k; ++c) {
      int n0 = c * ncn, n1 = min(n0 + ncn, N);
      if (n0 >= n1) break;
      msg_kernel<<<grid_m, 256, 0, stream>>>(
          (const unsigned int*)qB, (const unsigned int*)AB, edg, srcs, dsts, ews,
          eattr, WfB + (size_t)l * 2048, coff, msg, n0, n1, bound);
      stats_kernel<<<grid_s, 256, 0, stream>>>(msg, coff, stats, n0, n1, bound);
    }
    post_kernel<<<1280, 256, 0, stream>>>(
        h, stats, coff, adl,
        postW + (size_t)l * 13312, postB + (size_t)l * 32,
        linW + (size_t)l * 1024, linB + (size_t)l * 32, pre, pbuf, N);
    bn_reduce_kernel<<<1, 256, 0, stream>>>(pbuf, bn, 1280);
    bn_apply_kernel<<<(N * 32 + 255) / 256, 256, 0, stream>>>(pre, bn, bnG + (size_t)l * 32,
                                                              bnB + (size_t)l * 32, h, N);
  }
  pool_kernel<<<64, 256, 0, stream>>>(h, batch, gp, N);
  mlp_kernel<<<1, 256, 0, stream>>>(gp, W1, b1, W2, b2, W3, b3, out);
}

// Round 5
// 453.407 us; speedup vs baseline: 1.5488x; 1.4778x over previous
//
#include <hip/hip_runtime.h>

constexpr float kEps = 1e-5f;

__device__ __forceinline__ unsigned short f2bf(float x) {
  unsigned int u = __float_as_uint(x);
  unsigned int r = (u + 0x7fffu + ((u >> 16) & 1u)) >> 16;
  return (unsigned short)r;
}
__device__ __forceinline__ float bflo(unsigned int u) { return __uint_as_float(u << 16); }
__device__ __forceinline__ float bfhi(unsigned int u) { return __uint_as_float(u & 0xffff0000u); }
__device__ __forceinline__ unsigned int packbf(float a, float b) {
  return (unsigned int)f2bf(a) | ((unsigned int)f2bf(b) << 16);
}

// ---------------- setup kernels ----------------

__global__ void zero_int2(int* __restrict__ a, int* __restrict__ b, int n) {
  int i = blockIdx.x * blockDim.x + threadIdx.x;
  if (i < n) { a[i] = 0; b[i] = 0; }
}

__global__ void hist_kernel(const int* __restrict__ dst, int* __restrict__ deg, int E) {
  int e = blockIdx.x * blockDim.x + threadIdx.x;
  if (e < E) atomicAdd(&deg[dst[e]], 1);
}

__global__ void scan1_kernel(const int* __restrict__ deg, int* __restrict__ off,
                             int* __restrict__ part, int N) {
  __shared__ int sm[1024];
  int i = blockIdx.x * 1024 + threadIdx.x;
  int v = (i < N) ? deg[i] : 0;
  sm[threadIdx.x] = v;
  __syncthreads();
  for (int o = 1; o < 1024; o <<= 1) {
    int t = (threadIdx.x >= o) ? sm[threadIdx.x - o] : 0;
    __syncthreads();
    sm[threadIdx.x] += t;
    __syncthreads();
  }
  if (i < N) off[i] = sm[threadIdx.x] - v;   // exclusive
  if (threadIdx.x == 1023) part[blockIdx.x] = sm[1023];
}

__global__ void scan2_kernel(int* __restrict__ part, int* __restrict__ off, int nb, int N) {
  if (threadIdx.x == 0) {
    int run = 0;
    for (int b = 0; b < nb; b++) { int p = part[b]; part[b] = run; run += p; }
    off[N] = run;
  }
}

__global__ void scan3_kernel(int* __restrict__ off, const int* __restrict__ part, int N) {
  int i = blockIdx.x * 1024 + threadIdx.x;
  if (i < N) off[i] += part[blockIdx.x];
}

// CSR fill with direct scatter of src/ew (edge order within node = atomic
// arrival order; only perturbs fp reduction order at ulp level)
__global__ void fill_kernel(const int* __restrict__ src, const int* __restrict__ dst,
                            const float* __restrict__ ew, const int* __restrict__ off,
                            int* __restrict__ cnt, int* __restrict__ edg,
                            int* __restrict__ srcs, float* __restrict__ ews, int E) {
  int e = blockIdx.x * blockDim.x + threadIdx.x;
  if (e < E) {
    int d = dst[e];
    int slot = off[d] + atomicAdd(&cnt[d], 1);
    edg[slot] = e;
    srcs[slot] = src[e];
    ews[slot] = ew[e];
  }
}

// eattrg[slot][16] = eattr[edg[slot]][16]  (CSR-order edge features)
__global__ void egather_kernel(const int* __restrict__ edg, const float4* __restrict__ eattr4,
                               float4* __restrict__ eattrg4, int E4) {
  int i = blockIdx.x * blockDim.x + threadIdx.x;
  if (i < E4) {
    int slot = i >> 2, quad = i & 3;
    int e = edg[slot];
    eattrg4[i] = eattr4[e * 4 + quad];
  }
}

__global__ void adl_kernel(const int* __restrict__ deg, float* __restrict__ adl, int N) {
  __shared__ float sm[1024];
  float s = 0.f;
  for (int n = threadIdx.x; n < N; n += 1024) s += logf((float)deg[n] + 1.f);
  sm[threadIdx.x] = s;
  __syncthreads();
  for (int o = 512; o > 0; o >>= 1) {
    if (threadIdx.x < o) sm[threadIdx.x] += sm[threadIdx.x + o];
    __syncthreads();
  }
  if (threadIdx.x == 0) adl[0] = sm[0];   // sum of log(deg+1); consumers divide by N
}

// h0 = x @ node_W + node_b   (x: [N,128], W: [128,32])
__global__ void node_emb_kernel(const float* __restrict__ x, const float* __restrict__ W,
                                const float* __restrict__ b, float* __restrict__ h, int N) {
  int n = blockIdx.x * 8 + (threadIdx.x >> 5);
  int j = threadIdx.x & 31;
  if (n >= N) return;
  float acc = b[j];
  const float4* x4 = (const float4*)(x + (size_t)n * 128);
#pragma unroll
  for (int q = 0; q < 32; q++) {
    float4 v = x4[q];
    acc += v.x * W[(4 * q + 0) * 32 + j];
    acc += v.y * W[(4 * q + 1) * 32 + j];
    acc += v.z * W[(4 * q + 2) * 32 + j];
    acc += v.w * W[(4 * q + 3) * 32 + j];
  }
  h[n * 32 + j] = acc;
}

// Fold edge path: Wf[l,t] = (edge_W @ enc_W[l]) @ pre_W[l,t,64:96,:]  (16x32)
__global__ void fuse_kernel(const float* __restrict__ edge_W, const float* __restrict__ edge_b,
                            const float* __restrict__ enc_W, const float* __restrict__ enc_b,
                            const float* __restrict__ pre_W, const float* __restrict__ pre_b,
                            float* __restrict__ Wf, float* __restrict__ bf) {
  __shared__ float tW[2][16][32];
  __shared__ float tb[2][32];
  int tid = threadIdx.x;
  for (int i = tid; i < 1024; i += 256) {
    int l = i >> 9, r = (i >> 5) & 15, c = i & 31;
    float s = 0.f;
    for (int k = 0; k < 32; k++) s += edge_W[r * 32 + k] * enc_W[(l * 32 + k) * 32 + c];
    tW[l][r][c] = s;
  }
  for (int i = tid; i < 64; i += 256) {
    int l = i >> 5, c = i & 31;
    float s = enc_b[l * 32 + c];
    for (int k = 0; k < 32; k++) s += edge_b[k] * enc_W[(l * 32 + k) * 32 + c];
    tb[l][c] = s;
  }
  __syncthreads();
  for (int i = tid; i < 4096; i += 256) {
    int l = i >> 11, t = (i >> 9) & 3, r = (i >> 5) & 15, c = i & 31;
    float s = 0.f;
    for (int k = 0; k < 32; k++) s += tW[l][r][k] * pre_W[((l * 4 + t) * 96 + 64 + k) * 32 + c];
    Wf[i] = s;
  }
  for (int i = tid; i < 256; i += 256) {
    int l = i >> 7, t = (i >> 5) & 3, c = i & 31;
    float s = pre_b[(l * 4 + t) * 32 + c];
    for (int k = 0; k < 32; k++) s += tb[l][k] * pre_W[((l * 4 + t) * 96 + 64 + k) * 32 + c];
    bf[i] = s;
  }
}

// ---------------- per-layer: node pre-projection (+ bn zero) ----------------
__global__ __launch_bounds__(256) void prep_kernel(
    const float* __restrict__ h, const float* __restrict__ preW,
    const float* __restrict__ bfv, unsigned short* __restrict__ qB,
    unsigned short* __restrict__ AB, float* __restrict__ bn, int N) {
  if (blockIdx.x == 0 && threadIdx.x < 64) bn[threadIdx.x] = 0.f;
  __shared__ float hs[16][32];
  int tid = threadIdx.x;
  int c = tid & 127, half = tid >> 7;
  int t = c >> 5, g = c & 31;
  float ws[32], wd[32];
  {
    const float* pS = preW + (t * 96 + 32) * 32 + g;
    const float* pD = preW + (t * 96) * 32 + g;
#pragma unroll
    for (int k = 0; k < 32; k++) { ws[k] = pS[k * 32]; wd[k] = pD[k * 32]; }
  }
  float bc = bfv[c];
  int base = blockIdx.x * 16;
  for (int i = tid; i < 512; i += 256) {
    int nn = i >> 5;
    hs[nn][i & 31] = (base + nn < N) ? h[(size_t)(base + nn) * 32 + (i & 31)] : 0.f;
  }
  __syncthreads();
#pragma unroll
  for (int nn = 0; nn < 8; ++nn) {
    int nl = half + 2 * nn;
    int n = base + nl;
    if (n >= N) continue;
    float qa = 0.f, Aa = bc;
#pragma unroll
    for (int k = 0; k < 32; k++) {
      float hk = hs[nl][k];
      qa = fmaf(hk, ws[k], qa);
      Aa = fmaf(hk, wd[k], Aa);
    }
    qB[(size_t)n * 128 + c] = f2bf(qa);
    AB[(size_t)n * 128 + c] = f2bf(Aa);
  }
}

// ---------------- per-layer: fused batched aggregation ----------------
// 1 node/wave, edges in batches of 4: all gathers + broadcast eattr loads for
// the batch issue together (plus next-batch srcs prefetch) -> deep MLP.
#define FOLD8(F0, F1, VA, VB, O)                                           \
  F0 = fmaf(VA.x, wfa[O + 0], F0); F1 = fmaf(VA.x, wfb[O + 0], F1);        \
  F0 = fmaf(VA.y, wfa[O + 1], F0); F1 = fmaf(VA.y, wfb[O + 1], F1);        \
  F0 = fmaf(VA.z, wfa[O + 2], F0); F1 = fmaf(VA.z, wfb[O + 2], F1);        \
  F0 = fmaf(VA.w, wfa[O + 3], F0); F1 = fmaf(VA.w, wfb[O + 3], F1);        \
  F0 = fmaf(VB.x, wfa[O + 4], F0); F1 = fmaf(VB.x, wfb[O + 4], F1);        \
  F0 = fmaf(VB.y, wfa[O + 5], F0); F1 = fmaf(VB.y, wfb[O + 5], F1);        \
  F0 = fmaf(VB.z, wfa[O + 6], F0); F1 = fmaf(VB.z, wfb[O + 6], F1);        \
  F0 = fmaf(VB.w, wfa[O + 7], F0); F1 = fmaf(VB.w, wfb[O + 7], F1);

#define STATACC(V0, V1)                                                    \
  s0a += V0; sq0 = fmaf(V0, V0, sq0); mn0 = fminf(mn0, V0); mx0 = fmaxf(mx0, V0); \
  s1a += V1; sq1 = fmaf(V1, V1, sq1); mn1 = fminf(mn1, V1); mx1 = fmaxf(mx1, V1);

__global__ __launch_bounds__(256, 4) void agg3_kernel(
    const unsigned int* __restrict__ qB, const unsigned int* __restrict__ AB,
    const int* __restrict__ coff, const int* __restrict__ srcs,
    const float* __restrict__ ews, const float* __restrict__ eattrg,
    const float* __restrict__ Wf, unsigned int* __restrict__ stats, int N) {
  int lane = threadIdx.x & 63;
  int n = (blockIdx.x * blockDim.x + threadIdx.x) >> 6;
  if (n >= N) return;
  int t = lane >> 4, g0 = (2 * lane) & 31;
  float wfa[16], wfb[16];
  {
    const float* p = Wf + t * 512 + g0;
#pragma unroll
    for (int k = 0; k < 16; k++) { wfa[k] = p[k * 32]; wfb[k] = p[k * 32 + 1]; }
  }
  unsigned int au = AB[(size_t)n * 64 + lane];
  float a0 = bflo(au), a1 = bfhi(au);
  int beg = coff[n], end = coff[n + 1];
  int dg = end - beg;
  float s0a = 0.f, s1a = 0.f, sq0 = 0.f, sq1 = 0.f;
  float mn0 = 1e30f, mn1 = 1e30f, mx0 = -1e30f, mx1 = -1e30f;

  int i = beg;
  int sc0 = 0, sc1 = 0, sc2 = 0, sc3 = 0;
  if (i + 4 <= end) { sc0 = srcs[i]; sc1 = srcs[i + 1]; sc2 = srcs[i + 2]; sc3 = srcs[i + 3]; }
  for (; i + 4 <= end; i += 4) {
    unsigned int q0 = qB[(size_t)sc0 * 64 + lane];
    unsigned int q1 = qB[(size_t)sc1 * 64 + lane];
    unsigned int q2 = qB[(size_t)sc2 * 64 + lane];
    unsigned int q3 = qB[(size_t)sc3 * 64 + lane];
    float w0 = ews[i], w1 = ews[i + 1], w2 = ews[i + 2], w3 = ews[i + 3];
    const float4* ep = (const float4*)(eattrg + (size_t)i * 16);
    if (i + 8 <= end) { sc0 = srcs[i + 4]; sc1 = srcs[i + 5]; sc2 = srcs[i + 6]; sc3 = srcs[i + 7]; }
    float f00 = 0.f, f10 = 0.f, f01 = 0.f, f11 = 0.f;
    float f02 = 0.f, f12 = 0.f, f03 = 0.f, f13 = 0.f;
    {
      float4 aA = ep[0], aB = ep[1], bA = ep[4], bB = ep[5];
      float4 cA = ep[8], cB = ep[9], dA = ep[12], dB = ep[13];
      FOLD8(f00, f10, aA, aB, 0)
      FOLD8(f01, f11, bA, bB, 0)
      FOLD8(f02, f12, cA, cB, 0)
      FOLD8(f03, f13, dA, dB, 0)
    }
    {
      float4 aA = ep[2], aB = ep[3], bA = ep[6], bB = ep[7];
      float4 cA = ep[10], cB = ep[11], dA = ep[14], dB = ep[15];
      FOLD8(f00, f10, aA, aB, 8)
      FOLD8(f01, f11, bA, bB, 8)
      FOLD8(f02, f12, cA, cB, 8)
      FOLD8(f03, f13, dA, dB, 8)
    }
    float v0, v1;
    v0 = (a0 + bflo(q0) + f00) * w0; v1 = (a1 + bfhi(q0) + f10) * w0; STATACC(v0, v1)
    v0 = (a0 + bflo(q1) + f01) * w1; v1 = (a1 + bfhi(q1) + f11) * w1; STATACC(v0, v1)
    v0 = (a0 + bflo(q2) + f02) * w2; v1 = (a1 + bfhi(q2) + f12) * w2; STATACC(v0, v1)
    v0 = (a0 + bflo(q3) + f03) * w3; v1 = (a1 + bfhi(q3) + f13) * w3; STATACC(v0, v1)
  }
  for (; i < end; ++i) {
    int s = srcs[i];
    unsigned int q = qB[(size_t)s * 64 + lane];
    float w = ews[i];
    const float4* ep = (const float4*)(eattrg + (size_t)i * 16);
    float4 aA = ep[0], aB = ep[1], cA = ep[2], cB = ep[3];
    float f0 = 0.f, f1 = 0.f;
    FOLD8(f0, f1, aA, aB, 0)
    FOLD8(f0, f1, cA, cB, 8)
    float v0 = (a0 + bflo(q) + f0) * w;
    float v1 = (a1 + bfhi(q) + f1) * w;
    STATACC(v0, v1)
  }
  if (dg == 0) { mn0 = 0.f; mx0 = 0.f; mn1 = 0.f; mx1 = 0.f; }
  float inv = 1.f / (float)(dg > 0 ? dg : 1);
  float mean0 = s0a * inv, mean1 = s1a * inv;
  float sd0 = sqrtf(fmaxf(sq0 * inv - mean0 * mean0, 0.f) + kEps);
  float sd1 = sqrtf(fmaxf(sq1 * inv - mean1 * mean1, 0.f) + kEps);
  unsigned int* sp = stats + (size_t)n * 256;
  sp[0 * 64 + lane] = packbf(mean0, mean1);
  sp[1 * 64 + lane] = packbf(mn0, mn1);
  sp[2 * 64 + lane] = packbf(mx0, mx1);
  sp[3 * 64 + lane] = packbf(sd0, sd1);
}

// ---------------- per-layer: post_nn + lin + BN partials ----------------
// post_W staged packed-bf16 (26 KB LDS), stats kept as packed uints (4 KB).
__global__ __launch_bounds__(256) void post_kernel(
    const float* __restrict__ h, const unsigned int* __restrict__ stats,
    const int* __restrict__ coff, const float* __restrict__ adl,
    const float* __restrict__ postW, const float* __restrict__ postB,
    const float* __restrict__ linW, const float* __restrict__ linB,
    float* __restrict__ pre, float* __restrict__ bn, int N) {
  __shared__ unsigned int pwp[208 * 32];   // rows paired (2r,2r+1): 26 KB
  __shared__ unsigned int stu[4][256];     // per-wave raw stats rows: 4 KB
  __shared__ float red[8][32];             // BN partial reduce: 1 KB
  int tid = threadIdx.x;
  for (int i = tid; i < 6656; i += 256) {
    int r = i >> 5, cc = i & 31, tP = cc >> 3, gq = cc & 7;
    float lo = postW[tP * 3328 + (2 * r) * 8 + gq];
    float hi = postW[tP * 3328 + (2 * r + 1) * 8 + gq];
    pwp[i] = packbf(lo, hi);
  }
  __syncthreads();

  int wave = tid >> 6, lane = tid & 63;
  int c = lane & 31, hh = lane >> 5;
  int tP = c >> 3;
  float adN = adl[0];
  float bs = 0.f, bq = 0.f;

  for (int n = blockIdx.x * 4 + wave; n < N; n += gridDim.x * 4) {
    {
      uint4 su = ((const uint4*)stats)[(size_t)n * 64 + lane];
      ((uint4*)stu[wave])[lane] = su;   // per-wave region: no block barrier needed
    }
    int dg = coff[n + 1] - coff[n];
    float degc = (float)(dg > 0 ? dg : 1);
    float ad = adN / (float)N;
    float ld = logf(degc + 1.f);
    float amp = ld / ad, att = ad / ld;

    float acc = (hh == 0) ? postB[tP * 8 + (c & 7)] : 0.f;
    const float4* h4 = (const float4*)(h + (size_t)n * 32);
#pragma unroll
    for (int q4 = 0; q4 < 4; q4++) {
      float4 hv = h4[hh * 4 + q4];
      int r0 = hh * 8 + q4 * 2;
      unsigned int u0 = pwp[r0 * 32 + c], u1 = pwp[(r0 + 1) * 32 + c];
      acc = fmaf(hv.x, bflo(u0), acc);
      acc = fmaf(hv.y, bfhi(u0), acc);
      acc = fmaf(hv.z, bflo(u1), acc);
      acc = fmaf(hv.w, bfhi(u1), acc);
    }
#pragma unroll 8
    for (int jj = 0; jj < 32; jj++) {
      int sIdx = hh * 2 + (jj >> 4);
      unsigned int sv = stu[wave][sIdx * 64 + tP * 16 + (jj & 15)];
      float v0 = bflo(sv), v1 = bfhi(sv);
      int rm = 16 + hh * 32 + jj, ra = 80 + hh * 32 + jj, rt = 144 + hh * 32 + jj;
      unsigned int um = pwp[rm * 32 + c];
      unsigned int ua = pwp[ra * 32 + c];
      unsigned int ut = pwp[rt * 32 + c];
      float w0 = bflo(um); w0 = fmaf(amp, bflo(ua), w0); w0 = fmaf(att, bflo(ut), w0);
      float w1 = bfhi(um); w1 = fmaf(amp, bfhi(ua), w1); w1 = fmaf(att, bfhi(ut), w1);
      acc = fmaf(v0, w0, acc);
      acc = fmaf(v1, w1, acc);
    }
    acc += __shfl_xor(acc, 32);
    float o = linB[c];
#pragma unroll
    for (int k = 0; k < 32; k++) {
      float a = __shfl(acc, k);
      o = fmaf(a, linW[k * 32 + c], o);
    }
    if (lane < 32) {
      pre[(size_t)n * 32 + c] = o;
      bs += o;
      bq = fmaf(o, o, bq);
    }
  }

  __syncthreads();
  if (lane < 32) {
    red[wave * 2 + 0][c] = bs;
    red[wave * 2 + 1][c] = bq;
  }
  __syncthreads();
  if (tid < 64) {
    int which = tid >> 5, cc = tid & 31;
    float s = red[0 * 2 + which][cc] + red[1 * 2 + which][cc] +
              red[2 * 2 + which][cc] + red[3 * 2 + which][cc];
    atomicAdd(&bn[which * 32 + cc], s);
  }
}

__global__ void bn_apply_kernel(const float* __restrict__ pre, const float* __restrict__ bn,
                                const float* __restrict__ gamma, const float* __restrict__ beta,
                                float* __restrict__ h, int N) {
  int i = blockIdx.x * 256 + threadIdx.x;
  if (i >= N * 32) return;
  int j = i & 31;
  float invN = 1.f / (float)N;
  float mu = bn[j] * invN;
  float var = bn[32 + j] * invN - mu * mu;
  float is = rsqrtf(var + kEps);
  float v = (pre[i] - mu) * is * gamma[j] + beta[j];
  h[i] = fmaxf(v, 0.f);
}

// ---------------- pooling + MLP ----------------

__device__ __forceinline__ int lower_bound_dev(const int* a, int n, int key) {
  int lo = 0, hi = n;
  while (lo < hi) {
    int m = (lo + hi) >> 1;
    if (a[m] < key) lo = m + 1; else hi = m;
  }
  return lo;
}

__global__ void pool_kernel(const float* __restrict__ h, const int* __restrict__ batch,
                            float* __restrict__ gp, int N) {
  int gi = blockIdx.x;  // 64 graphs
  int lo = lower_bound_dev(batch, N, gi);
  int hi = lower_bound_dev(batch, N, gi + 1);
  __shared__ float part[8][32];
  int j = threadIdx.x & 31, ch = threadIdx.x >> 5;
  float s = 0.f;
  for (int n = lo + ch; n < hi; n += 8) s += h[(size_t)n * 32 + j];
  part[ch][j] = s;
  __syncthreads();
  if (threadIdx.x < 32) {
    float t = 0.f;
    for (int c2 = 0; c2 < 8; c2++) t += part[c2][j];
    gp[gi * 32 + j] = t;
  }
}

__global__ void mlp_kernel(const float* __restrict__ gp,
                           const float* __restrict__ W1, const float* __restrict__ b1,
                           const float* __restrict__ W2, const float* __restrict__ b2,
                           const float* __restrict__ W3, const float* __restrict__ b3,
                           float* __restrict__ out) {
  __shared__ float g1[64 * 32];
  __shared__ float g2[64 * 16];
  int tid = threadIdx.x;  // 256
  for (int i = tid; i < 2048; i += 256) {
    int r = i >> 5, c = i & 31;
    float s = b1[c];
    for (int k = 0; k < 32; k++) s += gp[r * 32 + k] * W1[k * 32 + c];
    g1[i] = fmaxf(s, 0.f);
  }
  __syncthreads();
  for (int i = tid; i < 1024; i += 256) {
    int r = i >> 4, c = i & 15;
    float s = b2[c];
    for (int k = 0; k < 32; k++) s += g1[r * 32 + k] * W2[k * 16 + c];
    g2[i] = fmaxf(s, 0.f);
  }
  __syncthreads();
  if (tid < 64) {
    float s = b3[0];
    for (int k = 0; k < 16; k++) s += g2[tid * 16 + k] * W3[k];
    out[tid] = s;
  }
}

// ---------------- launch ----------------

extern "C" void kernel_launch(void* const* d_in, const int* in_sizes, int n_in,
                              void* d_out, int out_size, void* d_ws, size_t ws_size,
                              hipStream_t stream) {
  (void)n_in; (void)out_size; (void)ws_size;
  const float* x     = (const float*)d_in[0];
  const float* eattr = (const float*)d_in[1];
  const float* ew    = (const float*)d_in[2];
  const int*   eidx  = (const int*)d_in[3];
  const int*   batch = (const int*)d_in[4];
  const float* nodeW = (const float*)d_in[5];
  const float* nodeB = (const float*)d_in[6];
  const float* edgeW = (const float*)d_in[7];
  const float* edgeB = (const float*)d_in[8];
  const float* encW  = (const float*)d_in[9];
  const float* encB  = (const float*)d_in[10];
  const float* preW  = (const float*)d_in[11];
  const float* preB  = (const float*)d_in[12];
  const float* postW = (const float*)d_in[13];
  const float* postB = (const float*)d_in[14];
  const float* linW  = (const float*)d_in[15];
  const float* linB  = (const float*)d_in[16];
  const float* bnG   = (const float*)d_in[17];
  const float* bnB   = (const float*)d_in[18];
  const float* W1    = (const float*)d_in[19];
  const float* b1    = (const float*)d_in[20];
  const float* W2    = (const float*)d_in[21];
  const float* b2    = (const float*)d_in[22];
  const float* W3    = (const float*)d_in[23];
  const float* b3    = (const float*)d_in[24];
  float* out = (float*)d_out;

  int N = in_sizes[0] / 128;
  int E = in_sizes[2];
  const int* srcp = eidx;
  const int* dstp = eidx + E;

  char* wsb = (char*)d_ws;
  size_t woff = 0;
  auto alloc = [&](size_t bytes) -> void* {
    void* p = (void*)(wsb + woff);
    woff += (bytes + 255) & ~(size_t)255;
    return p;
  };
  int* deg   = (int*)alloc((size_t)N * 4);
  int* cnt   = (int*)alloc((size_t)N * 4);
  int* coff  = (int*)alloc((size_t)(N + 1) * 4);
  int* part  = (int*)alloc(64 * 4);
  int* edg   = (int*)alloc((size_t)E * 4);
  int* srcs  = (int*)alloc((size_t)E * 4);
  float* ews = (float*)alloc((size_t)E * 4);
  float* eattrg = (float*)alloc((size_t)E * 16 * 4);
  float* h    = (float*)alloc((size_t)N * 32 * 4);
  float* pre  = (float*)alloc((size_t)N * 32 * 4);
  float* adl  = (float*)alloc(256);
  float* bn   = (float*)alloc(64 * 4);
  float* gp   = (float*)alloc(64 * 32 * 4);
  float* WfB  = (float*)alloc(2 * 4 * 16 * 32 * 4);
  float* bfB  = (float*)alloc(2 * 4 * 32 * 4);
  unsigned short* qB  = (unsigned short*)alloc((size_t)N * 128 * 2);
  unsigned short* AB  = (unsigned short*)alloc((size_t)N * 128 * 2);
  unsigned int* stats = (unsigned int*)alloc((size_t)N * 256 * 4);

  int nb = (N + 1023) / 1024;
  zero_int2<<<(N + 255) / 256, 256, 0, stream>>>(deg, cnt, N);
  hist_kernel<<<(E + 255) / 256, 256, 0, stream>>>(dstp, deg, E);
  scan1_kernel<<<nb, 1024, 0, stream>>>(deg, coff, part, N);
  scan2_kernel<<<1, 64, 0, stream>>>(part, coff, nb, N);
  scan3_kernel<<<nb, 1024, 0, stream>>>(coff, part, N);
  fill_kernel<<<(E + 255) / 256, 256, 0, stream>>>(srcp, dstp, ew, coff, cnt, edg, srcs, ews, E);
  egather_kernel<<<(E * 4 + 255) / 256, 256, 0, stream>>>(edg, (const float4*)eattr,
                                                          (float4*)eattrg, E * 4);
  adl_kernel<<<1, 1024, 0, stream>>>(deg, adl, N);
  node_emb_kernel<<<(N + 7) / 8, 256, 0, stream>>>(x, nodeW, nodeB, h, N);
  fuse_kernel<<<1, 256, 0, stream>>>(edgeW, edgeB, encW, encB, preW, preB, WfB, bfB);

  for (int l = 0; l < 2; l++) {
    prep_kernel<<<(N + 15) / 16, 256, 0, stream>>>(
        h, preW + (size_t)l * 12288, bfB + (size_t)l * 128, qB, AB, bn, N);
    agg3_kernel<<<(N + 3) / 4, 256, 0, stream>>>(
        (const unsigned int*)qB, (const unsigned int*)AB, coff, srcs, ews,
        eattrg, WfB + (size_t)l * 2048, stats, N);
    post_kernel<<<1280, 256, 0, stream>>>(
        h, stats, coff, adl,
        postW + (size_t)l * 13312, postB + (size_t)l * 32,
        linW + (size_t)l * 1024, linB + (size_t)l * 32, pre, bn, N);
    bn_apply_kernel<<<(N * 32 + 255) / 256, 256, 0, stream>>>(pre, bn, bnG + (size_t)l * 32,
                                                              bnB + (size_t)l * 32, h, N);
  }
  pool_kernel<<<64, 256, 0, stream>>>(h, batch, gp, N);
  mlp_kernel<<<1, 256, 0, stream>>>(gp, W1, b1, W2, b2, W3, b3, out);
}